// Round 1
// baseline (11296.126 us; speedup 1.0000x reference)
//
#include <hip/hip_runtime.h>

#define B_ 4
#define T_ 250
#define U_ 120
#define D_ 512
#define G_ 2048   // 4*D (gates)
#define O_ 1024   // odim

__device__ __forceinline__ float tanh_fast(float x){
  float e = __expf(2.f*x);
  return 1.f - 2.f/(e + 1.f);   // correct limits at +-inf
}
__device__ __forceinline__ float sigmoid_fast(float x){
  return 1.f/(1.f + __expf(-x));
}

__global__ void zero_ws_k(float* p, int n){
  int i = blockIdx.x*256 + threadIdx.x;
  if (i < n) p[i] = 0.f;
}

__global__ void gather_embed_k(const int* __restrict__ ys, const float* __restrict__ embed,
                               float* __restrict__ eys){
  int i = blockIdx.x*256 + threadIdx.x;
  if (i < B_*U_*D_){
    int r = i >> 9, k = i & 511;
    eys[i] = embed[ys[r]*D_ + k];
  }
}

// C[m][n] = bias[n] + sum_k A[m*lda+k]*B[n*ldb+k]
__global__ __launch_bounds__(256) void gemm_nt_k(
  const float* __restrict__ A, int lda,
  const float* __restrict__ B, int ldb,
  const float* __restrict__ bias,
  float* __restrict__ C, int ldc, int M, int N, int K)
{
  __shared__ float As[16][17], Bs[16][17];
  int tx = threadIdx.x, ty = threadIdx.y;
  int m = blockIdx.y*16 + ty;
  int n0 = blockIdx.x*16;
  float acc = 0.f;
  for (int k0 = 0; k0 < K; k0 += 16){
    As[ty][tx] = (m < M) ? A[m*lda + k0 + tx] : 0.f;
    int nb = n0 + ty;
    Bs[ty][tx] = (nb < N) ? B[nb*ldb + k0 + tx] : 0.f;
    __syncthreads();
#pragma unroll
    for (int kk=0;kk<16;kk++) acc += As[ty][kk] * Bs[tx][kk];
    __syncthreads();
  }
  int n = n0 + tx;
  if (m < M && n < N) C[m*ldc + n] = acc + (bias ? bias[n] : 0.f);
}

// C[m][n] = bias[n] + sum_k A[m*lda+k]*B[k*ldb+n]
__global__ __launch_bounds__(256) void gemm_nn_k(
  const float* __restrict__ A, int lda,
  const float* __restrict__ B, int ldb,
  const float* __restrict__ bias,
  float* __restrict__ C, int ldc, int M, int N, int K)
{
  __shared__ float As[16][17], Bs[16][17];
  int tx = threadIdx.x, ty = threadIdx.y;
  int m = blockIdx.y*16 + ty;
  int n = blockIdx.x*16 + tx;
  float acc = 0.f;
  for (int k0 = 0; k0 < K; k0 += 16){
    As[ty][tx] = (m < M) ? A[m*lda + k0 + tx] : 0.f;
    Bs[ty][tx] = (n < N) ? B[(k0+ty)*ldb + n] : 0.f;
    __syncthreads();
#pragma unroll
    for (int kk=0;kk<16;kk++) acc += As[ty][kk] * Bs[kk][tx];
    __syncthreads();
  }
  if (m < M && n < N) C[m*ldc + n] = acc + (bias ? bias[n] : 0.f);
}

// Wt[k*2048 + j] = W[j*ldw + k], j<2048, k<512. grid (64,16), block (32,8)
__global__ void transpose_k(const float* __restrict__ W, int ldw, float* __restrict__ Wt){
  __shared__ float t[32][33];
  int j0 = blockIdx.x*32, k0 = blockIdx.y*32;
  int tx = threadIdx.x, ty = threadIdx.y;
  for (int r=0;r<32;r+=8) t[ty+r][tx] = W[(size_t)(j0+ty+r)*ldw + k0 + tx];
  __syncthreads();
  for (int r=0;r<32;r+=8) Wt[(size_t)(k0+ty+r)*G_ + j0 + tx] = t[tx][ty+r];
}

// attention step: e = gvec . tanh(pre_enc + q), masked softmax, att_c = sum w*hs
// grid: 4 blocks (per b), 1024 threads
__global__ __launch_bounds__(1024) void att_k(
    const float* __restrict__ pre_enc, // (B,T,512)
    const float* __restrict__ q,       // (B,512)
    const float* __restrict__ gvec,    // (512)
    const int*  __restrict__ hlens,    // (B)
    const float* __restrict__ hs,      // (B,T,512)
    float* __restrict__ att_c)         // (B,512)
{
  int b = blockIdx.x;
  int tid = threadIdx.x;
  int lane = tid & 63, wv = tid >> 6;  // 16 waves
  __shared__ float q_s[512], gv_s[512], e_s[256], w_s[256], red_s[16];
  if (tid < 512){ q_s[tid] = q[b*512+tid]; gv_s[tid] = gvec[tid]; }
  __syncthreads();
  int hlen = hlens[b];
  const float* pe_b = pre_enc + (size_t)b*T_*512;
  for (int t = wv; t < T_; t += 16){
    const float* pe = pe_b + t*512 + lane*8;
    float s = 0.f;
#pragma unroll
    for (int i=0;i<8;i++)
      s += tanh_fast(pe[i] + q_s[lane*8+i]) * gv_s[lane*8+i];
    for (int off=32; off; off>>=1) s += __shfl_xor(s, off);
    if (lane==0) e_s[t] = s;
  }
  __syncthreads();
  float v = (tid < T_ && tid < hlen) ? e_s[tid] : -1e30f;
  float m = v;
  for (int off=32; off; off>>=1) m = fmaxf(m, __shfl_xor(m, off));
  if (lane==0) red_s[wv] = m;
  __syncthreads();
  if (tid==0){ float mm=red_s[0]; for(int i=1;i<16;i++) mm=fmaxf(mm,red_s[i]); red_s[0]=mm; }
  __syncthreads();
  float mx = red_s[0];
  float p = (tid < T_ && tid < hlen) ? __expf(v - mx) : 0.f;
  __syncthreads();
  float sum = p;
  for (int off=32; off; off>>=1) sum += __shfl_xor(sum, off);
  if (lane==0) red_s[wv] = sum;
  __syncthreads();
  if (tid==0){ float ss=0.f; for(int i=0;i<16;i++) ss+=red_s[i]; red_s[0]=ss; }
  __syncthreads();
  float denom = red_s[0];
  if (tid < 256) w_s[tid] = (tid < T_) ? p / denom : 0.f;
  __syncthreads();
  if (tid < 512){
    float acc = 0.f;
    const float* hsb = hs + (size_t)b*T_*512 + tid;
    for (int t=0; t<T_; t++) acc += w_s[t] * hsb[(size_t)t*512];
    att_c[b*512 + tid] = acc;
  }
}

// LSTM0: gates = pre0[u] + b_ih0 + b_hh0 + att_c@Wih0att^T + z0@Whh0^T
// grid 64: b=blk>>4, chunk=blk&15 (32 idx each); threads 256: kk=tid>>5, ii=tid&31
__global__ __launch_bounds__(256) void lstm0_k(
    const float* __restrict__ z0src, const float* __restrict__ c0src,
    float* __restrict__ z0dst, float* __restrict__ c0dst,
    const float* __restrict__ att_c,
    const float* __restrict__ Wt_hh0, const float* __restrict__ Wt_ih0att,
    const float* __restrict__ pre0,
    const float* __restrict__ b_ih0, const float* __restrict__ b_hh0, int u)
{
  int b = blockIdx.x >> 4, chunk = blockIdx.x & 15;
  int tid = threadIdx.x;
  int kk = tid >> 5, ii = tid & 31;
  int idx = chunk*32 + ii;
  __shared__ float z_s[512], a_s[512];
  __shared__ float red[8][4][32];
  for (int e = tid; e < 512; e += 256){ z_s[e] = z0src[b*512+e]; a_s[e] = att_c[b*512+e]; }
  __syncthreads();
  float acc[4] = {0.f,0.f,0.f,0.f};
  for (int k = kk*64; k < kk*64+64; k++){
    float zv = z_s[k], av = a_s[k];
    const float* wh = Wt_hh0    + (size_t)k*G_ + idx;
    const float* wa = Wt_ih0att + (size_t)k*G_ + idx;
#pragma unroll
    for (int g=0; g<4; g++) acc[g] += zv * wh[g*512] + av * wa[g*512];
  }
#pragma unroll
  for (int g=0; g<4; g++) red[kk][g][ii] = acc[g];
  __syncthreads();
  if (tid < 32){
    int idx2 = chunk*32 + tid;
    const float* p0 = pre0 + (size_t)(b*U_+u)*G_;
    float gate[4];
#pragma unroll
    for (int g=0; g<4; g++){
      float s = 0.f;
#pragma unroll
      for (int k2=0;k2<8;k2++) s += red[k2][g][tid];
      int j = g*512 + idx2;
      gate[g] = s + p0[j] + b_ih0[j] + b_hh0[j];
    }
    float ig = sigmoid_fast(gate[0]), fg = sigmoid_fast(gate[1]);
    float gg = tanh_fast(gate[2]),   og = sigmoid_fast(gate[3]);
    float cn = fg * c0src[b*512+idx2] + ig * gg;
    float hn = og * tanh_fast(cn);
    c0dst[b*512+idx2] = cn;
    z0dst[b*512+idx2] = hn;
  }
}

// LSTM1 + q for next step. grid 68: blocks 0..63 gates/activation, 64..67 q
__global__ __launch_bounds__(256) void lstm1_q_k(
    const float* __restrict__ z0new,
    const float* __restrict__ z1src, const float* __restrict__ c1src,
    float* __restrict__ z1dst, float* __restrict__ c1dst,
    const float* __restrict__ Wt_ih1, const float* __restrict__ Wt_hh1,
    const float* __restrict__ b_ih1, const float* __restrict__ b_hh1,
    const float* __restrict__ W_att_dec,
    float* __restrict__ q, float* __restrict__ h_dec, int u)
{
  int blk = blockIdx.x;
  int tid = threadIdx.x;
  if (blk < 64){
    int b = blk >> 4, chunk = blk & 15;
    int kk = tid >> 5, ii = tid & 31;
    int idx = chunk*32 + ii;
    __shared__ float x_s[512], h_s[512];
    __shared__ float red[8][4][32];
    for (int e=tid; e<512; e+=256){ x_s[e]=z0new[b*512+e]; h_s[e]=z1src[b*512+e]; }
    __syncthreads();
    float acc[4] = {0.f,0.f,0.f,0.f};
    for (int k=kk*64; k<kk*64+64; k++){
      float xv=x_s[k], hv=h_s[k];
      const float* wi = Wt_ih1 + (size_t)k*G_ + idx;
      const float* wh = Wt_hh1 + (size_t)k*G_ + idx;
#pragma unroll
      for (int g=0;g<4;g++) acc[g] += xv*wi[g*512] + hv*wh[g*512];
    }
#pragma unroll
    for (int g=0;g<4;g++) red[kk][g][ii]=acc[g];
    __syncthreads();
    if (tid < 32){
      int idx2 = chunk*32 + tid;
      float gate[4];
#pragma unroll
      for (int g=0;g<4;g++){
        float s=0.f;
#pragma unroll
        for (int k2=0;k2<8;k2++) s+=red[k2][g][tid];
        int j = g*512+idx2;
        gate[g] = s + b_ih1[j] + b_hh1[j];
      }
      float ig=sigmoid_fast(gate[0]), fg=sigmoid_fast(gate[1]);
      float gg=tanh_fast(gate[2]),   og=sigmoid_fast(gate[3]);
      float cn = fg*c1src[b*512+idx2] + ig*gg;
      float hn = og*tanh_fast(cn);
      c1dst[b*512+idx2]=cn; z1dst[b*512+idx2]=hn;
      h_dec[(size_t)(b*U_+u)*512 + idx2] = hn;
    }
  } else {
    int b = blk - 64;
    __shared__ float zq_s[512];
    for (int e=tid; e<512; e+=256) zq_s[e]=z0new[b*512+e];
    __syncthreads();
    float a0=0.f, a1=0.f;
    for (int k=0;k<512;k++){
      float zv = zq_s[k];
      a0 += zv * W_att_dec[(size_t)k*512 + tid];
      a1 += zv * W_att_dec[(size_t)k*512 + tid + 256];
    }
    q[b*512+tid]=a0; q[b*512+tid+256]=a1;
  }
}

// joint: out[b,t,u,o] = bias[o] + sum_j tanh(henc[b,t,j]+hdec[b,u,j]) * Wout[o,j]
// grid (8, 250, 4), block 256; tile 128 u-rows x 128 o-cols, 8x8 acc/thread
#define JKC 16
__global__ __launch_bounds__(256) void joint_k(
    const float* __restrict__ henc,   // (B*T, 512)
    const float* __restrict__ hdec,   // (B*U, 512)
    const float* __restrict__ Wout,   // (1024, 512)
    const float* __restrict__ bout,   // (1024)
    float* __restrict__ out)          // (B,T,U,1024)
{
  int ot = blockIdx.x;  // o tile (8 x 128)
  int t  = blockIdx.y;
  int b  = blockIdx.z;
  __shared__ float As[128][JKC+1];
  __shared__ float Bs[128][JKC+1];
  int tid = threadIdx.x;
  int tx = tid & 15, ty = tid >> 4;
  float acc[8][8] = {};
  const float* henc_row = henc + (size_t)(b*T_ + t)*512;
  for (int k0 = 0; k0 < 512; k0 += JKC){
#pragma unroll
    for (int i=0;i<8;i++){
      int e = tid*8+i; int r = e>>4, kk = e&15;
      float hv = henc_row[k0+kk];
      float dv = (r < U_) ? hdec[(size_t)(b*U_ + r)*512 + k0 + kk] : 0.f;
      As[r][kk] = tanh_fast(hv+dv);
      Bs[r][kk] = Wout[(size_t)(ot*128 + r)*512 + k0 + kk];
    }
    __syncthreads();
#pragma unroll
    for (int kk=0; kk<JKC; kk++){
      float a[8], bb[8];
#pragma unroll
      for (int i=0;i<8;i++) a[i]  = As[ty*8+i][kk];
#pragma unroll
      for (int j=0;j<8;j++) bb[j] = Bs[tx*8+j][kk];
#pragma unroll
      for (int i=0;i<8;i++)
#pragma unroll
        for (int j=0;j<8;j++)
          acc[i][j] += a[i]*bb[j];
    }
    __syncthreads();
  }
  int o0 = ot*128 + tx*8;
#pragma unroll
  for (int i=0;i<8;i++){
    int u = ty*8 + i;
    if (u < U_){
      float* op = out + ((size_t)(b*T_ + t)*U_ + u)*O_ + o0;
#pragma unroll
      for (int j=0;j<8;j++) op[j] = acc[i][j] + bout[o0+j];
    }
  }
}

extern "C" void kernel_launch(void* const* d_in, const int* in_sizes, int n_in,
                              void* d_out, int out_size, void* d_ws, size_t ws_size,
                              hipStream_t stream) {
  const float* hs       = (const float*)d_in[0];
  const int*   ys       = (const int*)  d_in[1];
  const int*   hlens    = (const int*)  d_in[2];
  const float* embed    = (const float*)d_in[3];
  const float* W_ih0    = (const float*)d_in[4];
  const float* b_ih0    = (const float*)d_in[5];
  const float* W_hh0    = (const float*)d_in[6];
  const float* b_hh0    = (const float*)d_in[7];
  const float* W_ih1    = (const float*)d_in[8];
  const float* b_ih1    = (const float*)d_in[9];
  const float* W_hh1    = (const float*)d_in[10];
  const float* b_hh1    = (const float*)d_in[11];
  const float* W_att_enc= (const float*)d_in[12];
  const float* b_att_enc= (const float*)d_in[13];
  const float* W_att_dec= (const float*)d_in[14];
  const float* gvec     = (const float*)d_in[15];
  const float* W_lin_enc= (const float*)d_in[16];
  const float* b_lin_enc= (const float*)d_in[17];
  const float* W_lin_dec= (const float*)d_in[18];
  const float* W_lin_out= (const float*)d_in[19];
  const float* b_lin_out= (const float*)d_in[20];
  float* out = (float*)d_out;

  float* w = (float*)d_ws;
  // ws layout (float offsets)
  float* z0    = w;              // [2][4*512]
  float* c0    = w + 4096;
  float* z1    = w + 8192;
  float* c1    = w + 12288;
  float* q     = w + 16384;      // [4*512]
  float* att_c = w + 18432;      // [4*512]
  float* eys   = w + 20480;      // [480*512]
  float* pre_enc = w + 266240;   // [1000*512]
  float* pre0    = w + 778240;   // [480*2048]
  float* henc    = w + 1761280;  // [1000*512]
  float* h_dec   = w + 2273280;  // [480*512]
  float* hdec_p  = w + 2519040;  // [480*512]
  float* Wt_hh0    = w + 2764800; // [512*2048]
  float* Wt_ih0att = w + 3813376;
  float* Wt_ih1    = w + 4861952;
  float* Wt_hh1    = w + 5910528;

  // init states+q+att_c to zero (first 20480 floats)
  zero_ws_k<<<80, 256, 0, stream>>>(w, 20480);
  // embedding gather
  gather_embed_k<<<(B_*U_*D_ + 255)/256, 256, 0, stream>>>(ys, embed, eys);
  // pre_enc = hs @ W_att_enc + b_att_enc   (1000x512, K=512)
  gemm_nn_k<<<dim3(32, 63), dim3(16,16), 0, stream>>>(hs, 512, W_att_enc, 512, b_att_enc,
                                                      pre_enc, 512, B_*T_, 512, 512);
  // pre0 = eys @ W_ih0[:, :512]^T  (480x2048, K=512)
  gemm_nt_k<<<dim3(128, 30), dim3(16,16), 0, stream>>>(eys, 512, W_ih0, 1024, nullptr,
                                                       pre0, 2048, B_*U_, 2048, 512);
  // weight transposes: Wt[k][j] = W[j][k]
  transpose_k<<<dim3(64,16), dim3(32,8), 0, stream>>>(W_hh0, 512, Wt_hh0);
  transpose_k<<<dim3(64,16), dim3(32,8), 0, stream>>>(W_ih0 + 512, 1024, Wt_ih0att);
  transpose_k<<<dim3(64,16), dim3(32,8), 0, stream>>>(W_ih1, 512, Wt_ih1);
  transpose_k<<<dim3(64,16), dim3(32,8), 0, stream>>>(W_hh1, 512, Wt_hh1);
  // henc = hs @ W_lin_enc^T + b_lin_enc (1000x512)
  gemm_nt_k<<<dim3(32, 63), dim3(16,16), 0, stream>>>(hs, 512, W_lin_enc, 512, b_lin_enc,
                                                      henc, 512, B_*T_, 512, 512);
  // sequential scan
  for (int u = 0; u < U_; ++u){
    int s = u & 1, d = 1 - s;
    att_k<<<4, 1024, 0, stream>>>(pre_enc, q, gvec, hlens, hs, att_c);
    lstm0_k<<<64, 256, 0, stream>>>(z0 + s*2048, c0 + s*2048, z0 + d*2048, c0 + d*2048,
                                    att_c, Wt_hh0, Wt_ih0att, pre0, b_ih0, b_hh0, u);
    lstm1_q_k<<<68, 256, 0, stream>>>(z0 + d*2048, z1 + s*2048, c1 + s*2048,
                                      z1 + d*2048, c1 + d*2048,
                                      Wt_ih1, Wt_hh1, b_ih1, b_hh1, W_att_dec,
                                      q, h_dec, u);
  }
  // hdec = h_dec @ W_lin_dec^T (480x512)
  gemm_nt_k<<<dim3(32, 30), dim3(16,16), 0, stream>>>(h_dec, 512, W_lin_dec, 512, nullptr,
                                                      hdec_p, 512, B_*U_, 512, 512);
  // joint
  joint_k<<<dim3(8, T_, B_), 256, 0, stream>>>(henc, hdec_p, W_lin_out, b_lin_out, out);
}

// Round 2
// 8299.857 us; speedup vs baseline: 1.3610x; 1.3610x over previous
//
#include <hip/hip_runtime.h>

#define B_ 4
#define T_ 250
#define U_ 120
#define D_ 512
#define G_ 2048   // 4*D (gates)
#define O_ 1024   // odim

typedef __attribute__((ext_vector_type(8))) short bf16x8;
typedef __attribute__((ext_vector_type(4))) float f32x4;
typedef __attribute__((ext_vector_type(4))) unsigned int ui4;

__device__ __forceinline__ float tanh_fast(float x){
  float e = __expf(2.f*x);
  return 1.f - 2.f/(e + 1.f);   // correct limits at +-inf
}
__device__ __forceinline__ float sigmoid_fast(float x){
  return 1.f/(1.f + __expf(-x));
}
__device__ __forceinline__ unsigned short f2bf(float x){
  unsigned int u = __float_as_uint(x);
  unsigned int r = (u + 0x7FFFu + ((u >> 16) & 1u)) >> 16;
  return (unsigned short)r;
}

__global__ void zero_ws_k(float* p, int n){
  int i = blockIdx.x*256 + threadIdx.x;
  if (i < n) p[i] = 0.f;
}

__global__ void gather_embed_k(const int* __restrict__ ys, const float* __restrict__ embed,
                               float* __restrict__ eys){
  int i = blockIdx.x*256 + threadIdx.x;
  if (i < B_*U_*D_){
    int r = i >> 9, k = i & 511;
    eys[i] = embed[ys[r]*D_ + k];
  }
}

// C[m][n] = bias[n] + sum_k A[m*lda+k]*B[n*ldb+k]
__global__ __launch_bounds__(256) void gemm_nt_k(
  const float* __restrict__ A, int lda,
  const float* __restrict__ B, int ldb,
  const float* __restrict__ bias,
  float* __restrict__ C, int ldc, int M, int N, int K)
{
  __shared__ float As[16][17], Bs[16][17];
  int tx = threadIdx.x, ty = threadIdx.y;
  int m = blockIdx.y*16 + ty;
  int n0 = blockIdx.x*16;
  float acc = 0.f;
  for (int k0 = 0; k0 < K; k0 += 16){
    As[ty][tx] = (m < M) ? A[m*lda + k0 + tx] : 0.f;
    int nb = n0 + ty;
    Bs[ty][tx] = (nb < N) ? B[nb*ldb + k0 + tx] : 0.f;
    __syncthreads();
#pragma unroll
    for (int kk=0;kk<16;kk++) acc += As[ty][kk] * Bs[tx][kk];
    __syncthreads();
  }
  int n = n0 + tx;
  if (m < M && n < N) C[m*ldc + n] = acc + (bias ? bias[n] : 0.f);
}

// C[m][n] = bias[n] + sum_k A[m*lda+k]*B[k*ldb+n]
__global__ __launch_bounds__(256) void gemm_nn_k(
  const float* __restrict__ A, int lda,
  const float* __restrict__ B, int ldb,
  const float* __restrict__ bias,
  float* __restrict__ C, int ldc, int M, int N, int K)
{
  __shared__ float As[16][17], Bs[16][17];
  int tx = threadIdx.x, ty = threadIdx.y;
  int m = blockIdx.y*16 + ty;
  int n = blockIdx.x*16 + tx;
  float acc = 0.f;
  for (int k0 = 0; k0 < K; k0 += 16){
    As[ty][tx] = (m < M) ? A[m*lda + k0 + tx] : 0.f;
    Bs[ty][tx] = (n < N) ? B[(k0+ty)*ldb + n] : 0.f;
    __syncthreads();
#pragma unroll
    for (int kk=0;kk<16;kk++) acc += As[ty][kk] * Bs[kk][tx];
    __syncthreads();
  }
  if (m < M && n < N) C[m*ldc + n] = acc + (bias ? bias[n] : 0.f);
}

// Wt[k*2048 + j] = W[j*ldw + k], j<2048, k<512. grid (64,16), block (32,8)
__global__ void transpose_k(const float* __restrict__ W, int ldw, float* __restrict__ Wt){
  __shared__ float t[32][33];
  int j0 = blockIdx.x*32, k0 = blockIdx.y*32;
  int tx = threadIdx.x, ty = threadIdx.y;
  for (int r=0;r<32;r+=8) t[ty+r][tx] = W[(size_t)(j0+ty+r)*ldw + k0 + tx];
  __syncthreads();
  for (int r=0;r<32;r+=8) Wt[(size_t)(k0+ty+r)*G_ + j0 + tx] = t[tx][ty+r];
}

// attention step
__global__ __launch_bounds__(1024) void att_k(
    const float* __restrict__ pre_enc, const float* __restrict__ q,
    const float* __restrict__ gvec, const int* __restrict__ hlens,
    const float* __restrict__ hs, float* __restrict__ att_c)
{
  int b = blockIdx.x;
  int tid = threadIdx.x;
  int lane = tid & 63, wv = tid >> 6;  // 16 waves
  __shared__ float q_s[512], gv_s[512], e_s[256], w_s[256], red_s[16];
  if (tid < 512){ q_s[tid] = q[b*512+tid]; gv_s[tid] = gvec[tid]; }
  __syncthreads();
  int hlen = hlens[b];
  const float* pe_b = pre_enc + (size_t)b*T_*512;
  for (int t = wv; t < T_; t += 16){
    const float* pe = pe_b + t*512 + lane*8;
    float s = 0.f;
#pragma unroll
    for (int i=0;i<8;i++)
      s += tanh_fast(pe[i] + q_s[lane*8+i]) * gv_s[lane*8+i];
    for (int off=32; off; off>>=1) s += __shfl_xor(s, off);
    if (lane==0) e_s[t] = s;
  }
  __syncthreads();
  float v = (tid < T_ && tid < hlen) ? e_s[tid] : -1e30f;
  float m = v;
  for (int off=32; off; off>>=1) m = fmaxf(m, __shfl_xor(m, off));
  if (lane==0) red_s[wv] = m;
  __syncthreads();
  if (tid==0){ float mm=red_s[0]; for(int i=1;i<16;i++) mm=fmaxf(mm,red_s[i]); red_s[0]=mm; }
  __syncthreads();
  float mx = red_s[0];
  float p = (tid < T_ && tid < hlen) ? __expf(v - mx) : 0.f;
  __syncthreads();
  float sum = p;
  for (int off=32; off; off>>=1) sum += __shfl_xor(sum, off);
  if (lane==0) red_s[wv] = sum;
  __syncthreads();
  if (tid==0){ float ss=0.f; for(int i=0;i<16;i++) ss+=red_s[i]; red_s[0]=ss; }
  __syncthreads();
  float denom = red_s[0];
  if (tid < 256) w_s[tid] = (tid < T_) ? p / denom : 0.f;
  __syncthreads();
  if (tid < 512){
    float acc = 0.f;
    const float* hsb = hs + (size_t)b*T_*512 + tid;
    for (int t=0; t<T_; t++) acc += w_s[t] * hsb[(size_t)t*512];
    att_c[b*512 + tid] = acc;
  }
}

// LSTM0
__global__ __launch_bounds__(256) void lstm0_k(
    const float* __restrict__ z0src, const float* __restrict__ c0src,
    float* __restrict__ z0dst, float* __restrict__ c0dst,
    const float* __restrict__ att_c,
    const float* __restrict__ Wt_hh0, const float* __restrict__ Wt_ih0att,
    const float* __restrict__ pre0,
    const float* __restrict__ b_ih0, const float* __restrict__ b_hh0, int u)
{
  int b = blockIdx.x >> 4, chunk = blockIdx.x & 15;
  int tid = threadIdx.x;
  int kk = tid >> 5, ii = tid & 31;
  int idx = chunk*32 + ii;
  __shared__ float z_s[512], a_s[512];
  __shared__ float red[8][4][32];
  for (int e = tid; e < 512; e += 256){ z_s[e] = z0src[b*512+e]; a_s[e] = att_c[b*512+e]; }
  __syncthreads();
  float acc[4] = {0.f,0.f,0.f,0.f};
  for (int k = kk*64; k < kk*64+64; k++){
    float zv = z_s[k], av = a_s[k];
    const float* wh = Wt_hh0    + (size_t)k*G_ + idx;
    const float* wa = Wt_ih0att + (size_t)k*G_ + idx;
#pragma unroll
    for (int g=0; g<4; g++) acc[g] += zv * wh[g*512] + av * wa[g*512];
  }
#pragma unroll
  for (int g=0; g<4; g++) red[kk][g][ii] = acc[g];
  __syncthreads();
  if (tid < 32){
    int idx2 = chunk*32 + tid;
    const float* p0 = pre0 + (size_t)(b*U_+u)*G_;
    float gate[4];
#pragma unroll
    for (int g=0; g<4; g++){
      float s = 0.f;
#pragma unroll
      for (int k2=0;k2<8;k2++) s += red[k2][g][tid];
      int j = g*512 + idx2;
      gate[g] = s + p0[j] + b_ih0[j] + b_hh0[j];
    }
    float ig = sigmoid_fast(gate[0]), fg = sigmoid_fast(gate[1]);
    float gg = tanh_fast(gate[2]),   og = sigmoid_fast(gate[3]);
    float cn = fg * c0src[b*512+idx2] + ig * gg;
    float hn = og * tanh_fast(cn);
    c0dst[b*512+idx2] = cn;
    z0dst[b*512+idx2] = hn;
  }
}

// LSTM1 + q
__global__ __launch_bounds__(256) void lstm1_q_k(
    const float* __restrict__ z0new,
    const float* __restrict__ z1src, const float* __restrict__ c1src,
    float* __restrict__ z1dst, float* __restrict__ c1dst,
    const float* __restrict__ Wt_ih1, const float* __restrict__ Wt_hh1,
    const float* __restrict__ b_ih1, const float* __restrict__ b_hh1,
    const float* __restrict__ W_att_dec,
    float* __restrict__ q, float* __restrict__ h_dec, int u)
{
  int blk = blockIdx.x;
  int tid = threadIdx.x;
  if (blk < 64){
    int b = blk >> 4, chunk = blk & 15;
    int kk = tid >> 5, ii = tid & 31;
    int idx = chunk*32 + ii;
    __shared__ float x_s[512], h_s[512];
    __shared__ float red[8][4][32];
    for (int e=tid; e<512; e+=256){ x_s[e]=z0new[b*512+e]; h_s[e]=z1src[b*512+e]; }
    __syncthreads();
    float acc[4] = {0.f,0.f,0.f,0.f};
    for (int k=kk*64; k<kk*64+64; k++){
      float xv=x_s[k], hv=h_s[k];
      const float* wi = Wt_ih1 + (size_t)k*G_ + idx;
      const float* wh = Wt_hh1 + (size_t)k*G_ + idx;
#pragma unroll
      for (int g=0;g<4;g++) acc[g] += xv*wi[g*512] + hv*wh[g*512];
    }
#pragma unroll
    for (int g=0;g<4;g++) red[kk][g][ii]=acc[g];
    __syncthreads();
    if (tid < 32){
      int idx2 = chunk*32 + tid;
      float gate[4];
#pragma unroll
      for (int g=0;g<4;g++){
        float s=0.f;
#pragma unroll
        for (int k2=0;k2<8;k2++) s+=red[k2][g][tid];
        int j = g*512+idx2;
        gate[g] = s + b_ih1[j] + b_hh1[j];
      }
      float ig=sigmoid_fast(gate[0]), fg=sigmoid_fast(gate[1]);
      float gg=tanh_fast(gate[2]),   og=sigmoid_fast(gate[3]);
      float cn = fg*c1src[b*512+idx2] + ig*gg;
      float hn = og*tanh_fast(cn);
      c1dst[b*512+idx2]=cn; z1dst[b*512+idx2]=hn;
      h_dec[(size_t)(b*U_+u)*512 + idx2] = hn;
    }
  } else {
    int b = blk - 64;
    __shared__ float zq_s[512];
    for (int e=tid; e<512; e+=256) zq_s[e]=z0new[b*512+e];
    __syncthreads();
    float a0=0.f, a1=0.f;
    for (int k=0;k<512;k++){
      float zv = zq_s[k];
      a0 += zv * W_att_dec[(size_t)k*512 + tid];
      a1 += zv * W_att_dec[(size_t)k*512 + tid + 256];
    }
    q[b*512+tid]=a0; q[b*512+tid+256]=a1;
  }
}

// ---------- fallback f32 joint (used only if ws too small for bf16 path) ----
#define JKC 16
__global__ __launch_bounds__(256) void joint_k(
    const float* __restrict__ henc, const float* __restrict__ hdec,
    const float* __restrict__ Wout, const float* __restrict__ bout,
    float* __restrict__ out)
{
  int ot = blockIdx.x;
  int t  = blockIdx.y;
  int b  = blockIdx.z;
  __shared__ float As[128][JKC+1];
  __shared__ float Bs[128][JKC+1];
  int tid = threadIdx.x;
  int tx = tid & 15, ty = tid >> 4;
  float acc[8][8] = {};
  const float* henc_row = henc + (size_t)(b*T_ + t)*512;
  for (int k0 = 0; k0 < 512; k0 += JKC){
#pragma unroll
    for (int i=0;i<8;i++){
      int e = tid*8+i; int r = e>>4, kk = e&15;
      float hv = henc_row[k0+kk];
      float dv = (r < U_) ? hdec[(size_t)(b*U_ + r)*512 + k0 + kk] : 0.f;
      As[r][kk] = tanh_fast(hv+dv);
      Bs[r][kk] = Wout[(size_t)(ot*128 + r)*512 + k0 + kk];
    }
    __syncthreads();
#pragma unroll
    for (int kk=0; kk<JKC; kk++){
      float a[8], bb[8];
#pragma unroll
      for (int i=0;i<8;i++) a[i]  = As[ty*8+i][kk];
#pragma unroll
      for (int j=0;j<8;j++) bb[j] = Bs[tx*8+j][kk];
#pragma unroll
      for (int i=0;i<8;i++)
#pragma unroll
        for (int j=0;j<8;j++)
          acc[i][j] += a[i]*bb[j];
    }
    __syncthreads();
  }
  int o0 = ot*128 + tx*8;
#pragma unroll
  for (int i=0;i<8;i++){
    int u = ty*8 + i;
    if (u < U_){
      float* op = out + ((size_t)(b*T_ + t)*U_ + u)*O_ + o0;
#pragma unroll
      for (int j=0;j<8;j++) op[j] = acc[i][j] + bout[o0+j];
    }
  }
}

// ---------- bf16 MFMA joint path ----------
// P[bt*120+u][k] = tanh(henc[bt][k] + hdec[b*120+u][k]) as bf16
__global__ __launch_bounds__(256) void tanh_pack_k(
    const float* __restrict__ henc, const float* __restrict__ hdec,
    unsigned short* __restrict__ P)
{
  int i = blockIdx.x*256 + threadIdx.x;   // one thread per 8 elems
  if (i >= B_*T_*U_*512/8) return;
  int e = i*8;
  int k = e & 511;
  int r = e >> 9;           // row in 0..B*T*U-1
  int u = r % U_;
  int bt = r / U_;
  int b = bt / T_;
  const float* hp = henc + (size_t)bt*512 + k;
  const float* dp = hdec + (size_t)(b*U_ + u)*512 + k;
  unsigned int w[4];
#pragma unroll
  for (int j=0;j<4;j++){
    unsigned short lo = f2bf(tanh_fast(hp[2*j]   + dp[2*j]));
    unsigned short hi = f2bf(tanh_fast(hp[2*j+1] + dp[2*j+1]));
    w[j] = (unsigned int)lo | ((unsigned int)hi << 16);
  }
  ui4* dst = (ui4*)(P + e);
  *dst = ui4{w[0], w[1], w[2], w[3]};
}

__global__ __launch_bounds__(256) void wconv_k(const float* __restrict__ W,
                                               unsigned short* __restrict__ Wb, int n8){
  int i = blockIdx.x*256 + threadIdx.x;
  if (i >= n8) return;
  int e = i*8;
  unsigned int w[4];
#pragma unroll
  for (int j=0;j<4;j++){
    unsigned short lo = f2bf(W[e+2*j]);
    unsigned short hi = f2bf(W[e+2*j+1]);
    w[j] = (unsigned int)lo | ((unsigned int)hi << 16);
  }
  *(ui4*)(Wb + e) = ui4{w[0], w[1], w[2], w[3]};
}

// joint GEMM: out[bt,u,o] = bias[o] + sum_k P[bt*120+u][k] * Wb[o][k]
// grid (8, T, B), 256 threads = 4 waves (2x2), tile 128x128, BK=64
__global__ __launch_bounds__(256) void joint_mfma_k(
    const unsigned short* __restrict__ P,   // (B*T*120, 512) bf16
    const unsigned short* __restrict__ Wb,  // (1024, 512) bf16
    const float* __restrict__ bout,
    float* __restrict__ out)
{
  __shared__ unsigned short As[128*64];   // 16 KB, row stride 128 B, XOR-swizzled
  __shared__ unsigned short Bs[128*64];
  int tid = threadIdx.x;
  int lane = tid & 63;
  int w = tid >> 6, wr = w >> 1, wc = w & 1;
  int o0 = blockIdx.x * 128;
  int t = blockIdx.y, b = blockIdx.z;
  int bt = b*T_ + t;
  const char* Pbase = (const char*)(P + (size_t)bt*U_*512);
  const char* Wbase = (const char*)(Wb + (size_t)o0*512);

  f32x4 acc[4][4] = {};

  for (int k0 = 0; k0 < 512; k0 += 64){
    __syncthreads();
#pragma unroll
    for (int j=0;j<4;j++){
      int pos = (j*256 + tid)*16;          // linear byte pos in tile
      int row = pos >> 7;                  // 128 B per row
      int inrow = pos & 127;
      int srcin = inrow ^ ((row & 7) << 4);  // inverse-swizzled source (rule #21)
      int arow = row < U_ ? row : (U_-1);    // clamp padded rows
      __builtin_amdgcn_global_load_lds(
        (const __attribute__((address_space(1))) void*)(Pbase + (size_t)arow*1024 + k0*2 + srcin),
        (__attribute__((address_space(3))) void*)((char*)As + pos), 16, 0, 0);
      __builtin_amdgcn_global_load_lds(
        (const __attribute__((address_space(1))) void*)(Wbase + (size_t)row*1024 + k0*2 + srcin),
        (__attribute__((address_space(3))) void*)((char*)Bs + pos), 16, 0, 0);
    }
    __syncthreads();
#pragma unroll
    for (int kk=0; kk<2; kk++){
      bf16x8 a[4], bb[4];
#pragma unroll
      for (int m=0;m<4;m++){
        int row = wr*64 + m*16 + (lane & 15);
        int inrow = (kk*64 + (lane >> 4)*16) ^ ((row & 7) << 4);
        a[m] = *(const bf16x8*)((const char*)As + row*128 + inrow);
      }
#pragma unroll
      for (int n=0;n<4;n++){
        int row = wc*64 + n*16 + (lane & 15);
        int inrow = (kk*64 + (lane >> 4)*16) ^ ((row & 7) << 4);
        bb[n] = *(const bf16x8*)((const char*)Bs + row*128 + inrow);
      }
#pragma unroll
      for (int m=0;m<4;m++)
#pragma unroll
        for (int n=0;n<4;n++)
          acc[m][n] = __builtin_amdgcn_mfma_f32_16x16x32_bf16(a[m], bb[n], acc[m][n], 0, 0, 0);
    }
  }
  // epilogue: C[row=(lane>>4)*4+reg (u side), col=lane&15 (o side)]
#pragma unroll
  for (int n=0;n<4;n++){
    int o = o0 + wc*64 + n*16 + (lane & 15);
    float bias = bout[o];
#pragma unroll
    for (int m=0;m<4;m++){
      int ubase = wr*64 + m*16 + ((lane >> 4) << 2);
#pragma unroll
      for (int r=0;r<4;r++){
        int u = ubase + r;
        if (u < U_)
          out[((size_t)bt*U_ + u)*O_ + o] = acc[m][n][r] + bias;
      }
    }
  }
}

extern "C" void kernel_launch(void* const* d_in, const int* in_sizes, int n_in,
                              void* d_out, int out_size, void* d_ws, size_t ws_size,
                              hipStream_t stream) {
  const float* hs       = (const float*)d_in[0];
  const int*   ys       = (const int*)  d_in[1];
  const int*   hlens    = (const int*)  d_in[2];
  const float* embed    = (const float*)d_in[3];
  const float* W_ih0    = (const float*)d_in[4];
  const float* b_ih0    = (const float*)d_in[5];
  const float* W_hh0    = (const float*)d_in[6];
  const float* b_hh0    = (const float*)d_in[7];
  const float* W_ih1    = (const float*)d_in[8];
  const float* b_ih1    = (const float*)d_in[9];
  const float* W_hh1    = (const float*)d_in[10];
  const float* b_hh1    = (const float*)d_in[11];
  const float* W_att_enc= (const float*)d_in[12];
  const float* b_att_enc= (const float*)d_in[13];
  const float* W_att_dec= (const float*)d_in[14];
  const float* gvec     = (const float*)d_in[15];
  const float* W_lin_enc= (const float*)d_in[16];
  const float* b_lin_enc= (const float*)d_in[17];
  const float* W_lin_dec= (const float*)d_in[18];
  const float* W_lin_out= (const float*)d_in[19];
  const float* b_lin_out= (const float*)d_in[20];
  float* out = (float*)d_out;

  float* w = (float*)d_ws;
  // ws layout (float offsets)
  float* z0    = w;              // [2][4*512]
  float* c0    = w + 4096;
  float* z1    = w + 8192;
  float* c1    = w + 12288;
  float* q     = w + 16384;      // [4*512]
  float* att_c = w + 18432;      // [4*512]
  float* eys   = w + 20480;      // [480*512]
  float* pre_enc = w + 266240;   // [1000*512]
  float* pre0    = w + 778240;   // [480*2048]
  float* henc    = w + 1761280;  // [1000*512]
  float* h_dec   = w + 2273280;  // [480*512]
  float* hdec_p  = w + 2519040;  // [480*512]
  float* Wt_hh0    = w + 2764800; // [512*2048]
  float* Wt_ih0att = w + 3813376;
  float* Wt_ih1    = w + 4861952;
  float* Wt_hh1    = w + 5910528; // ends at 6959104 floats
  unsigned short* Pbf = (unsigned short*)(w + 6959104);   // 61,440,000 bf16
  unsigned short* Wbf = (unsigned short*)(w + 6959104 + 30720000); // 524,288 bf16
  const size_t ws_needed = (size_t)(6959104 + 30720000 + 262144) * 4;

  zero_ws_k<<<80, 256, 0, stream>>>(w, 20480);
  gather_embed_k<<<(B_*U_*D_ + 255)/256, 256, 0, stream>>>(ys, embed, eys);
  gemm_nn_k<<<dim3(32, 63), dim3(16,16), 0, stream>>>(hs, 512, W_att_enc, 512, b_att_enc,
                                                      pre_enc, 512, B_*T_, 512, 512);
  gemm_nt_k<<<dim3(128, 30), dim3(16,16), 0, stream>>>(eys, 512, W_ih0, 1024, nullptr,
                                                       pre0, 2048, B_*U_, 2048, 512);
  transpose_k<<<dim3(64,16), dim3(32,8), 0, stream>>>(W_hh0, 512, Wt_hh0);
  transpose_k<<<dim3(64,16), dim3(32,8), 0, stream>>>(W_ih0 + 512, 1024, Wt_ih0att);
  transpose_k<<<dim3(64,16), dim3(32,8), 0, stream>>>(W_ih1, 512, Wt_ih1);
  transpose_k<<<dim3(64,16), dim3(32,8), 0, stream>>>(W_hh1, 512, Wt_hh1);
  gemm_nt_k<<<dim3(32, 63), dim3(16,16), 0, stream>>>(hs, 512, W_lin_enc, 512, b_lin_enc,
                                                      henc, 512, B_*T_, 512, 512);
  for (int u = 0; u < U_; ++u){
    int s = u & 1, d = 1 - s;
    att_k<<<4, 1024, 0, stream>>>(pre_enc, q, gvec, hlens, hs, att_c);
    lstm0_k<<<64, 256, 0, stream>>>(z0 + s*2048, c0 + s*2048, z0 + d*2048, c0 + d*2048,
                                    att_c, Wt_hh0, Wt_ih0att, pre0, b_ih0, b_hh0, u);
    lstm1_q_k<<<68, 256, 0, stream>>>(z0 + d*2048, z1 + s*2048, c1 + s*2048,
                                      z1 + d*2048, c1 + d*2048,
                                      Wt_ih1, Wt_hh1, b_ih1, b_hh1, W_att_dec,
                                      q, h_dec, u);
  }
  gemm_nt_k<<<dim3(32, 30), dim3(16,16), 0, stream>>>(h_dec, 512, W_lin_dec, 512, nullptr,
                                                      hdec_p, 512, B_*U_, 512, 512);

  if (ws_size >= ws_needed){
    tanh_pack_k<<<(B_*T_*U_*512/8 + 255)/256, 256, 0, stream>>>(henc, hdec_p, Pbf);
    wconv_k<<<(O_*512/8 + 255)/256, 256, 0, stream>>>(W_lin_out, Wbf, O_*512/8);
    joint_mfma_k<<<dim3(8, T_, B_), 256, 0, stream>>>(Pbf, Wbf, b_lin_out, out);
  } else {
    joint_k<<<dim3(8, T_, B_), 256, 0, stream>>>(henc, hdec_p, W_lin_out, b_lin_out, out);
  }
}